// Round 4
// baseline (478.072 us; speedup 1.0000x reference)
//
#include <hip/hip_runtime.h>

#define N_TOK 16384
#define HID   4096
#define N_EXP 64
#define TOPK  8

#define SPLIT 4
#define KS    (HID / SPLIT)    // 1024 k per block
#define TBLK  128              // tokens per block (4 waves x 32)

// d_out layout (floats, concatenated in reference return order)
#define OFF_WT   (N_TOK * N_EXP)
#define OFF_IDX  (OFF_WT + N_TOK * TOPK)
#define OFF_MASK (OFF_IDX + N_TOK * TOPK)

typedef __attribute__((ext_vector_type(8))) short bf16x8;
typedef __attribute__((ext_vector_type(4))) float f32x4;

__device__ __forceinline__ unsigned short f2bf(float f) {
    unsigned u = __float_as_uint(f);
    u += 0x7FFFu + ((u >> 16) & 1u);          // RNE
    return (unsigned short)(u >> 16);
}
__device__ __forceinline__ float bf2f(unsigned short h) {
    return __uint_as_float((unsigned)h << 16);
}

// ---------------------------------------------------------------------------
// W fp32 -> 3-term bf16 split (hi/mid/lo = 24 mantissa bits, ~exact fp32).
// 64x4096 elements; grid 256 x 256, 4 elements/thread.
// ---------------------------------------------------------------------------
__global__ __launch_bounds__(256)
void wconv(const float* __restrict__ W, unsigned short* __restrict__ Wh,
           unsigned short* __restrict__ Wm, unsigned short* __restrict__ Wl)
{
    const int i = (blockIdx.x * 256 + threadIdx.x) * 4;
    float4 w = *(const float4*)(W + i);
    ushort4 h, m, l;
#pragma unroll
    for (int j = 0; j < 4; ++j) {
        float v = ((const float*)&w)[j];
        unsigned short hh = f2bf(v); float r1 = v - bf2f(hh);   // exact residual
        unsigned short mm = f2bf(r1); float r2 = r1 - bf2f(mm); // exact residual
        unsigned short ll = f2bf(r2);
        ((unsigned short*)&h)[j] = hh;
        ((unsigned short*)&m)[j] = mm;
        ((unsigned short*)&l)[j] = ll;
    }
    *(ushort4*)(Wh + i) = h;
    *(ushort4*)(Wm + i) = m;
    *(ushort4*)(Wl + i) = l;
}

// ---------------------------------------------------------------------------
// Kernel A: router += x @ W^T via 6-term bf16x3 MFMA (fp32-accurate).
// Grid = 128 token-blocks x SPLIT. Block: 4 waves x 32 tokens = 128 tok x 64 exp.
// Wave: 2 m-tiles x 4 n-tiles of 16x16x32 MFMA. Zero LDS; A-frags converted
// from coalesced fp32 global loads; B-frags from pre-split bf16 W (L2-hot).
// A-frag: A[m=lane&15][k=quad*8+j]; B-frag: B^T rows likewise (W is [E][H]).
// C/D:    col(expert)=lane&15, row(token)=quad*4+reg.  [m89/m120 verified]
// ---------------------------------------------------------------------------
__global__ __launch_bounds__(256, 2)
void router_mfma(const float* __restrict__ x,
                 const unsigned short* __restrict__ Wh,
                 const unsigned short* __restrict__ Wm,
                 const unsigned short* __restrict__ Wl,
                 float* __restrict__ router)
{
    const int tid  = threadIdx.x;
    const int lane = tid & 63;
    const int wv   = tid >> 6;
    const int tb   = blockIdx.x & 127;   // token block
    const int ksl  = blockIdx.x >> 7;    // k slice
    const int m16  = lane & 15;
    const int quad = lane >> 4;
    const long t0  = (long)tb * TBLK + wv * 32;
    const int kb   = ksl * KS + quad * 8;

    f32x4 acc[2][4];
#pragma unroll
    for (int a = 0; a < 2; ++a)
#pragma unroll
        for (int n = 0; n < 4; ++n) acc[a][n] = (f32x4){0.f, 0.f, 0.f, 0.f};

    const float* xp0 = x + (t0 + m16) * (long)HID + kb;
    const float* xp1 = x + (t0 + 16 + m16) * (long)HID + kb;
    const unsigned short* wh = Wh + (long)m16 * HID + kb;
    const unsigned short* wm = Wm + (long)m16 * HID + kb;
    const unsigned short* wl = Wl + (long)m16 * HID + kb;

    float4 nx[4];                               // x prefetch (the HBM stream)
    nx[0] = *(const float4*)(xp0);
    nx[1] = *(const float4*)(xp0 + 4);
    nx[2] = *(const float4*)(xp1);
    nx[3] = *(const float4*)(xp1 + 4);

    for (int k = 0; k < KS; k += 32) {
        float4 cx[4];
#pragma unroll
        for (int j = 0; j < 4; ++j) cx[j] = nx[j];
        if (k + 32 < KS) {
            nx[0] = *(const float4*)(xp0 + k + 32);
            nx[1] = *(const float4*)(xp0 + k + 36);
            nx[2] = *(const float4*)(xp1 + k + 32);
            nx[3] = *(const float4*)(xp1 + k + 36);
        }

        // B-frags for all 4 n-tiles, 3 terms (L2-resident bf16 W)
        bf16x8 Bh[4], Bm[4], Bl[4];
#pragma unroll
        for (int n = 0; n < 4; ++n) {
            const long wo = (long)(n * 16) * HID + k;
            Bh[n] = *(const bf16x8*)(wh + wo);
            Bm[n] = *(const bf16x8*)(wm + wo);
            Bl[n] = *(const bf16x8*)(wl + wo);
        }

        // convert 16 fp32 -> 3-term bf16 A-frags
        bf16x8 Ah[2], Am[2], Al[2];
#pragma unroll
        for (int mt = 0; mt < 2; ++mt) {
            const float* p = (const float*)&cx[2 * mt];
#pragma unroll
            for (int j = 0; j < 8; ++j) {
                float v = p[j];
                unsigned short hh = f2bf(v); float r1 = v - bf2f(hh);
                unsigned short mm = f2bf(r1); float r2 = r1 - bf2f(mm);
                unsigned short ll = f2bf(r2);
                Ah[mt][j] = (short)hh; Am[mt][j] = (short)mm; Al[mt][j] = (short)ll;
            }
        }

        // 6 term-pairs x 8 independent tiles (interleaved for MFMA latency)
#pragma unroll
        for (int n = 0; n < 4; ++n)
#pragma unroll
            for (int mt = 0; mt < 2; ++mt)
                acc[mt][n] = __builtin_amdgcn_mfma_f32_16x16x32_bf16(Ah[mt], Bh[n], acc[mt][n], 0, 0, 0);
#pragma unroll
        for (int n = 0; n < 4; ++n)
#pragma unroll
            for (int mt = 0; mt < 2; ++mt)
                acc[mt][n] = __builtin_amdgcn_mfma_f32_16x16x32_bf16(Ah[mt], Bm[n], acc[mt][n], 0, 0, 0);
#pragma unroll
        for (int n = 0; n < 4; ++n)
#pragma unroll
            for (int mt = 0; mt < 2; ++mt)
                acc[mt][n] = __builtin_amdgcn_mfma_f32_16x16x32_bf16(Am[mt], Bh[n], acc[mt][n], 0, 0, 0);
#pragma unroll
        for (int n = 0; n < 4; ++n)
#pragma unroll
            for (int mt = 0; mt < 2; ++mt)
                acc[mt][n] = __builtin_amdgcn_mfma_f32_16x16x32_bf16(Ah[mt], Bl[n], acc[mt][n], 0, 0, 0);
#pragma unroll
        for (int n = 0; n < 4; ++n)
#pragma unroll
            for (int mt = 0; mt < 2; ++mt)
                acc[mt][n] = __builtin_amdgcn_mfma_f32_16x16x32_bf16(Al[mt], Bh[n], acc[mt][n], 0, 0, 0);
#pragma unroll
        for (int n = 0; n < 4; ++n)
#pragma unroll
            for (int mt = 0; mt < 2; ++mt)
                acc[mt][n] = __builtin_amdgcn_mfma_f32_16x16x32_bf16(Am[mt], Bm[n], acc[mt][n], 0, 0, 0);
    }

    // epilogue: split-K partials via HW fp32 atomics (router pre-zeroed)
#pragma unroll
    for (int mt = 0; mt < 2; ++mt)
#pragma unroll
        for (int n = 0; n < 4; ++n)
#pragma unroll
            for (int r = 0; r < 4; ++r) {
                long tok = t0 + mt * 16 + quad * 4 + r;
                int  e   = n * 16 + m16;
                unsafeAtomicAdd(router + tok * (long)N_EXP + e, acc[mt][n][r]);
            }
}

// ---------------------------------------------------------------------------
// Kernel B: add bias, rewrite router logits, softmax + top-8 (tie -> lowest
// index) + renormalized weights. Wave per token.
// ---------------------------------------------------------------------------
__global__ __launch_bounds__(256)
void router_topk(float* __restrict__ router, const float* __restrict__ b,
                 float* __restrict__ out)
{
    const int tid  = threadIdx.x;
    const int lane = tid & 63;
    const int wv   = tid >> 6;
    const int n    = blockIdx.x * 4 + wv;

    float l = router[(long)n * N_EXP + lane] + b[lane];
    router[(long)n * N_EXP + lane] = l;   // full logit output

    float m = l;
#pragma unroll
    for (int o = 32; o > 0; o >>= 1) m = fmaxf(m, __shfl_xor(m, o));
    float p = expf(l - m);
    float Z = p;
#pragma unroll
    for (int o = 32; o > 0; o >>= 1) Z += __shfl_xor(Z, o);
    float prob = p / Z;

    float cur = prob;
    float myv = 0.f;
    int   myi = 0;
    float ssum = 0.f;
#pragma unroll
    for (int k = 0; k < TOPK; ++k) {
        float v = cur;
        int   id = lane;
#pragma unroll
        for (int o = 32; o > 0; o >>= 1) {
            float ov = __shfl_xor(v, o);
            int   oi = __shfl_xor(id, o);
            if (ov > v || (ov == v && oi < id)) { v = ov; id = oi; }
        }
        if (lane == k)  { myv = v; myi = id; }
        if (lane == id) cur = -1.f;
        ssum += v;
    }

    if (lane < TOPK) {
        out[OFF_WT  + (long)n * TOPK + lane] = myv / ssum;
        out[OFF_IDX + (long)n * TOPK + lane] = (float)myi;
    }
}

// ---------------------------------------------------------------------------
// Kernel C: dense one-hot mask writer. mask[e][k][n] = (idx[n][k]==e).
// ---------------------------------------------------------------------------
__global__ __launch_bounds__(256)
void mask_fill(const float* __restrict__ idxf, float* __restrict__ mask)
{
    const int k  = blockIdx.x >> 4;                      // 0..7
    const int n0 = ((blockIdx.x & 15) * 256 + threadIdx.x) * 4;

    int sel[4];
#pragma unroll
    for (int t = 0; t < 4; ++t)
        sel[t] = (int)idxf[(long)(n0 + t) * TOPK + k];

#pragma unroll 8
    for (int e = 0; e < N_EXP; ++e) {
        float4 v;
        v.x = (sel[0] == e) ? 1.0f : 0.0f;
        v.y = (sel[1] == e) ? 1.0f : 0.0f;
        v.z = (sel[2] == e) ? 1.0f : 0.0f;
        v.w = (sel[3] == e) ? 1.0f : 0.0f;
        *(float4*)(mask + (long)(e * TOPK + k) * N_TOK + n0) = v;
    }
}

extern "C" void kernel_launch(void* const* d_in, const int* in_sizes, int n_in,
                              void* d_out, int out_size, void* d_ws, size_t ws_size,
                              hipStream_t stream)
{
    const float* x = (const float*)d_in[0];
    const float* W = (const float*)d_in[1];
    const float* b = (const float*)d_in[2];
    float* out = (float*)d_out;

    unsigned short* Wh = (unsigned short*)d_ws;
    unsigned short* Wm = Wh + (size_t)N_EXP * HID;
    unsigned short* Wl = Wm + (size_t)N_EXP * HID;

    // zero only the router region (atomic accumulation target)
    hipMemsetAsync(out, 0, (size_t)(N_TOK * N_EXP) * sizeof(float), stream);

    hipLaunchKernelGGL(wconv, dim3(N_EXP * HID / 1024), dim3(256), 0, stream,
                       W, Wh, Wm, Wl);
    hipLaunchKernelGGL(router_mfma, dim3(128 * SPLIT), dim3(256), 0, stream,
                       x, Wh, Wm, Wl, out);
    hipLaunchKernelGGL(router_topk, dim3(N_TOK / 4), dim3(256), 0, stream,
                       out, b, out);
    hipLaunchKernelGGL(mask_fill, dim3(128), dim3(256), 0, stream,
                       out + OFF_IDX, out + OFF_MASK);
}